// Round 8
// baseline (1719.600 us; speedup 1.0000x reference)
//
#include <hip/hip_runtime.h>
#include <math.h>

// Problem constants
#define S 64
#define F 10
#define K 7
#define D 512
#define HH 196   // H*H = 14*14
#define DT 128
#define NF (S*F)          // 640
#define NROWS_V (S*F*K)   // 4480
#define NROWS_A (S*K)     // 448
#define NOUT (S*K*F)      // 4480
#define MLP_R 16
#define NA_BLK (NROWS_A / MLP_R)   // 28
#define NV_BLK (NROWS_V / MLP_R)   // 280

// fg geometry: 16-channel tiles (16 ch x 196 hw = 12,544 B contiguous), 16 tiles
#define FG_TPB 256
#define FG_NT 16
#define FG_TILE_F4 784
#define FG_SLOTS 832   // 13 issues x 64 lanes (slots >=784 junk, never read)

// Measurement reps (this round only): each kernel repeats its full work so the
// dispatch exceeds the ~147us harness poison-fills and surfaces in rocprof
// top-5 with counters. zoff==0 at runtime; compiler can't prove it, so loads
// can't be hoisted across reps. Output identical each rep -> deterministic.
#define FG_REPS 4
#define MLP_REPS 20
#define LOSS_REPS 64

// ---------------------------------------------------------------------------
// Kernel 1 (v7): fg[n][k][c] = (sum_hw feat[n][c][hw]*cam[n][k][hw]) / (cam_sum+1e-10)
// DS-pressure fix: cam slice lives in REGISTERS (21 float4/thread, loaded once,
// reused across all 16 tiles). Per wave-tile DS is now just 3-4 ds_read_b128
// (feat from staged LDS) + 28 shfl. 256 thr: 16 ch x 16 hw-split; 4-level
// shuffle reduce within 16-lane groups; s16==0 lane stores 7 channels' outputs.
// Staging: contiguous global_load_lds, double-buffered, 1-deep overlap.
// ---------------------------------------------------------------------------
__device__ __forceinline__ void fg_stage(const float* region, float4* dst,
                                         int wave, int lane) {
#pragma unroll
  for (int i = wave; i < 13; i += 4) {
    const int p = i * 64 + lane;
    const int ps = (p < FG_TILE_F4) ? p : 0;  // clamp tail (junk slots, never read)
    __builtin_amdgcn_global_load_lds(
        (const __attribute__((address_space(1))) void*)(region + (size_t)ps * 4),
        (__attribute__((address_space(3))) void*)(dst + i * 64), 16, 0, 0);
  }
}

__global__ __launch_bounds__(FG_TPB) void fg_kernel(
    const float* __restrict__ feat, const float* __restrict__ cam,
    float* __restrict__ fg, int reps, size_t zoff) {
  __shared__ float4 buf[2][FG_SLOTS];   // 26,624 B
  __shared__ float inv_lds[K];

  const int t = threadIdx.x;
  const int lane = t & 63;
  const int wave = t >> 6;
  const int n = blockIdx.x >> 1;
  const int half = blockIdx.x & 1;
  const int c0blk = half * 256;
  const int cl = t >> 4;   // channel-in-tile 0..15
  const int s16 = t & 15;  // 16-way hw split

  for (int r = 0; r < reps; ++r) {
    const float* featn = feat + r * zoff + ((size_t)n * D + c0blk) * HH;
    const float* camn = cam + r * zoff + (size_t)n * K * HH;
    const float4* camf4 = reinterpret_cast<const float4*>(camn);

    // cam slice -> registers (coalesced: 16 consecutive threads read 16
    // consecutive float4). Reused across all 16 tiles.
    float4 cq0[K], cq1[K], cq2[K], cq3[K];
#pragma unroll
    for (int k = 0; k < K; ++k) {
      cq0[k] = camf4[k * 49 + s16];
      cq1[k] = camf4[k * 49 + 16 + s16];
      cq2[k] = camf4[k * 49 + 32 + s16];
      cq3[k] = (s16 == 0) ? camf4[k * 49 + 48] : make_float4(0.f, 0.f, 0.f, 0.f);
    }

    // cam sums -> inv_lds (wave 0 butterfly)
    if (t < 64) {
      const bool act = lane < 49;
#pragma unroll
      for (int k = 0; k < K; ++k) {
        float4 cv = act ? camf4[k * 49 + lane] : make_float4(0.f, 0.f, 0.f, 0.f);
        float s = cv.x + cv.y + cv.z + cv.w;
#pragma unroll
        for (int m = 32; m >= 1; m >>= 1) s += __shfl_xor(s, m, 64);
        if (lane == 0) inv_lds[k] = 1.0f / (s + 1e-10f);
      }
    }

    fg_stage(featn, &buf[0][0], wave, lane);
    __syncthreads();  // stage(0) landed + inv_lds published

    float invr[K];
#pragma unroll
    for (int k = 0; k < K; ++k) invr[k] = inv_lds[k];

    float* fgn = fg + (size_t)n * K * D;

    for (int tt = 0; tt < FG_NT; ++tt) {
      const int cur = tt & 1;
      if (tt < FG_NT - 1)
        fg_stage(featn + (size_t)(tt + 1) * FG_TILE_F4 * 4,
                 &buf[cur ^ 1][0], wave, lane);

      const float4* tb = &buf[cur][0] + cl * 49;
      const float4 f0 = tb[s16];
      const float4 f1 = tb[16 + s16];
      const float4 f2 = tb[32 + s16];
      const float4 f3 = (s16 == 0) ? tb[48] : make_float4(0.f, 0.f, 0.f, 0.f);

      float acc[K];
#pragma unroll
      for (int k = 0; k < K; ++k) {
        float a = 0.f;
        a = fmaf(f0.x, cq0[k].x, a); a = fmaf(f0.y, cq0[k].y, a);
        a = fmaf(f0.z, cq0[k].z, a); a = fmaf(f0.w, cq0[k].w, a);
        a = fmaf(f1.x, cq1[k].x, a); a = fmaf(f1.y, cq1[k].y, a);
        a = fmaf(f1.z, cq1[k].z, a); a = fmaf(f1.w, cq1[k].w, a);
        a = fmaf(f2.x, cq2[k].x, a); a = fmaf(f2.y, cq2[k].y, a);
        a = fmaf(f2.z, cq2[k].z, a); a = fmaf(f2.w, cq2[k].w, a);
        a = fmaf(f3.x, cq3[k].x, a); a = fmaf(f3.y, cq3[k].y, a);
        a = fmaf(f3.z, cq3[k].z, a); a = fmaf(f3.w, cq3[k].w, a);
        acc[k] = a;
      }
#pragma unroll
      for (int m = 1; m <= 8; m <<= 1) {
#pragma unroll
        for (int k = 0; k < K; ++k) acc[k] += __shfl_xor(acc[k], m, 64);
      }
      if (s16 == 0) {
        const int c = c0blk + tt * 16 + cl;
#pragma unroll
        for (int k = 0; k < K; ++k) fgn[k * D + c] = acc[k] * invr[k];
      }
      __syncthreads();  // next tile landed (vmcnt drained) + buf reuse guard
    }
    __syncthreads();  // rep boundary: inv_lds rewrite guard
  }
}

// ---------------------------------------------------------------------------
// Kernel 2 (v3): BOTH MLPs, 16 rows/block x 512 threads (1 row x 4 cols per
// thread). Halves W re-streaming from L2 vs 8-row blocks.
// ---------------------------------------------------------------------------
__device__ __forceinline__ void fma4(float4& acc, float sx, const float4& wv) {
  acc.x += sx * wv.x; acc.y += sx * wv.y; acc.z += sx * wv.z; acc.w += sx * wv.w;
}

__global__ __launch_bounds__(512) void mlp2_kernel(
    const float* __restrict__ Xa, const float* __restrict__ Xv,
    const float* __restrict__ W1a, const float* __restrict__ b1a,
    const float* __restrict__ W2a, const float* __restrict__ b2a,
    const float* __restrict__ ga, const float* __restrict__ bna,
    const float* __restrict__ W1v, const float* __restrict__ b1v,
    const float* __restrict__ W2v, const float* __restrict__ b2v,
    const float* __restrict__ gv, const float* __restrict__ bnv,
    float* __restrict__ Ta, float* __restrict__ Tv, int reps, size_t zoff) {
  __shared__ float xs[MLP_R * D];
  __shared__ float hs[MLP_R * DT];
  const int t = threadIdx.x;
  const int b = blockIdx.x;

  for (int r = 0; r < reps; ++r) {
    const float *X, *W1, *b1, *W2, *b2, *g, *bn;
    float* out;
    int r0;
    if (b < NA_BLK) {
      X = Xa; W1 = W1a; b1 = b1a; W2 = W2a; b2 = b2a; g = ga; bn = bna;
      out = Ta; r0 = b * MLP_R;
    } else {
      X = Xv; W1 = W1v; b1 = b1v; W2 = W2v; b2 = b2v; g = gv; bn = bnv;
      out = Tv; r0 = (b - NA_BLK) * MLP_R;
    }
    X += r * zoff; W1 += r * zoff; W2 += r * zoff;

    {
      const float4* src = reinterpret_cast<const float4*>(X + (size_t)r0 * D);
      float4* dst = reinterpret_cast<float4*>(xs);
#pragma unroll
      for (int i = 0; i < 4; ++i) dst[t + i * 512] = src[t + i * 512];
    }
    __syncthreads();

    const int j0 = (t & 31) * 4;
    const int rt = t >> 5;  // 0..15

    float4 a0 = *reinterpret_cast<const float4*>(b1 + j0);
    for (int d = 0; d < D; d += 4) {
      float4 xa = *reinterpret_cast<const float4*>(xs + rt * D + d);
      float4 w0 = *reinterpret_cast<const float4*>(W1 + (size_t)(d + 0) * DT + j0);
      float4 w1 = *reinterpret_cast<const float4*>(W1 + (size_t)(d + 1) * DT + j0);
      float4 w2 = *reinterpret_cast<const float4*>(W1 + (size_t)(d + 2) * DT + j0);
      float4 w3 = *reinterpret_cast<const float4*>(W1 + (size_t)(d + 3) * DT + j0);
      fma4(a0, xa.x, w0); fma4(a0, xa.y, w1); fma4(a0, xa.z, w2); fma4(a0, xa.w, w3);
    }
    a0.x = fmaxf(a0.x, 0.f); a0.y = fmaxf(a0.y, 0.f);
    a0.z = fmaxf(a0.z, 0.f); a0.w = fmaxf(a0.w, 0.f);
    *reinterpret_cast<float4*>(hs + rt * DT + j0) = a0;
    __syncthreads();

    float4 c0 = *reinterpret_cast<const float4*>(b2 + j0);
    for (int d = 0; d < DT; d += 4) {
      float4 xa = *reinterpret_cast<const float4*>(hs + rt * DT + d);
      float4 w0 = *reinterpret_cast<const float4*>(W2 + (size_t)(d + 0) * DT + j0);
      float4 w1 = *reinterpret_cast<const float4*>(W2 + (size_t)(d + 1) * DT + j0);
      float4 w2 = *reinterpret_cast<const float4*>(W2 + (size_t)(d + 2) * DT + j0);
      float4 w3 = *reinterpret_cast<const float4*>(W2 + (size_t)(d + 3) * DT + j0);
      fma4(c0, xa.x, w0); fma4(c0, xa.y, w1); fma4(c0, xa.z, w2); fma4(c0, xa.w, w3);
    }
    float4 gvv = *reinterpret_cast<const float4*>(g + j0);
    float4 bv = *reinterpret_cast<const float4*>(bn + j0);
    float4 o0;
    o0.x = c0.x * gvv.x + bv.x; o0.y = c0.y * gvv.y + bv.y;
    o0.z = c0.z * gvv.z + bv.z; o0.w = c0.w * gvv.w + bv.w;
    *reinterpret_cast<float4*>(out + (size_t)(r0 + rt) * DT + j0) = o0;
    __syncthreads();  // rep boundary: xs/hs reuse guard
  }
}

// ---------------------------------------------------------------------------
// Kernel 3: losses + masks (8 units/block, 32-lane groups).
// ---------------------------------------------------------------------------
__global__ __launch_bounds__(256) void loss_kernel(
    const float* __restrict__ Ta, const float* __restrict__ Tv,
    const float* __restrict__ pred_a, const float* __restrict__ pred_v,
    const int* __restrict__ perm_idx, const int* __restrict__ cls_idx,
    float* __restrict__ out, int reps, size_t zoff) {
  const int t = threadIdx.x;
  const int sub = t & 31;
  const int idx = blockIdx.x * 8 + (t >> 5);
  const int f = idx % F;
  const int k = (idx / F) % K;
  const int s = idx / (K * F);

  for (int r = 0; r < reps; ++r) {
    const float* Tar = Ta + r * zoff;
    const float* Tvr = Tv + r * zoff;
    const int p = (perm_idx + r * zoff)[idx];
    const int c = (cls_idx + r * zoff)[idx];
    const int rowd = ((s ^ 1) * F + p) * K + c;

    float4 ta = reinterpret_cast<const float4*>(Tar)[(s * K + k) * 32 + sub];
    float4 tv = reinterpret_cast<const float4*>(Tvr)[((s * F + f) * K + k) * 32 + sub];
    float4 td = reinterpret_cast<const float4*>(Tvr)[rowd * 32 + sub];
    float d1 = 0.f, d2 = 0.f, e;
    e = ta.x - tv.x; d1 += e * e;
    e = ta.y - tv.y; d1 += e * e;
    e = ta.z - tv.z; d1 += e * e;
    e = ta.w - tv.w; d1 += e * e;
    e = ta.x - td.x; d2 += e * e;
    e = ta.y - td.y; d2 += e * e;
    e = ta.z - td.z; d2 += e * e;
    e = ta.w - td.w; d2 += e * e;
#pragma unroll
    for (int m = 16; m >= 1; m >>= 1) {
      d1 += __shfl_xor(d1, m, 64);
      d2 += __shfl_xor(d2, m, 64);
    }
    if (sub == 0) {
      float pa = (pred_a + r * zoff)[s * K + k];
      bool act = pa > 0.3f;
      int num = (int)floorf(pa * (float)F);
      float pvv = (pred_v + r * zoff)[(s * F + f) * K + k];
      float sg = 1.0f / (1.0f + expf(-pvv));
      bool mco = act && (sg > 0.3f);
      bool mdi = act && (f < num);
      float lco = d1 * (1.0f / 128.0f);
      float ldi = d2 * (1.0f / 128.0f);
      out[idx] = mco ? lco : 0.0f;
      out[NOUT + idx] = mdi ? ldi : 0.0f;
      out[2 * NOUT + idx] = mco ? 1.0f : 0.0f;
      out[3 * NOUT + idx] = mdi ? 1.0f : 0.0f;
    }
  }
}

extern "C" void kernel_launch(void* const* d_in, const int* in_sizes, int n_in,
                              void* d_out, int out_size, void* d_ws, size_t ws_size,
                              hipStream_t stream) {
  const float* feat_a     = (const float*)d_in[0];
  const float* pred_a     = (const float*)d_in[1];
  const float* feat_v_raw = (const float*)d_in[2];
  const float* pred_v     = (const float*)d_in[3];
  const float* cam        = (const float*)d_in[4];
  const float* W1a = (const float*)d_in[5];
  const float* b1a = (const float*)d_in[6];
  const float* W2a = (const float*)d_in[7];
  const float* b2a = (const float*)d_in[8];
  const float* ga  = (const float*)d_in[9];
  const float* bna = (const float*)d_in[10];
  const float* W1v = (const float*)d_in[11];
  const float* b1v = (const float*)d_in[12];
  const float* W2v = (const float*)d_in[13];
  const float* b2v = (const float*)d_in[14];
  const float* gv  = (const float*)d_in[15];
  const float* bnv = (const float*)d_in[16];
  const int* perm_idx = (const int*)d_in[17];
  const int* cls_idx  = (const int*)d_in[18];
  float* out = (float*)d_out;

  // workspace layout (floats): fg[640*7*512] | Ta[448*128] | Tv[4480*128]
  float* ws = (float*)d_ws;
  float* fg = ws;
  float* Ta = fg + (size_t)NF * K * D;
  float* Tv = Ta + (size_t)NROWS_A * DT;

  fg_kernel<<<NF * 2, FG_TPB, 0, stream>>>(feat_v_raw, cam, fg, FG_REPS, (size_t)0);
  mlp2_kernel<<<NA_BLK + NV_BLK, 512, 0, stream>>>(
      feat_a, fg, W1a, b1a, W2a, b2a, ga, bna,
      W1v, b1v, W2v, b2v, gv, bnv, Ta, Tv, MLP_REPS, (size_t)0);
  loss_kernel<<<NOUT / 8, 256, 0, stream>>>(Ta, Tv, pred_a, pred_v, perm_idx,
                                            cls_idx, out, LOSS_REPS, (size_t)0);
}

// Round 9
// 95.715 us; speedup vs baseline: 17.9659x; 17.9659x over previous
//
#include <hip/hip_runtime.h>
#include <math.h>

// Problem constants
#define S 64
#define F 10
#define K 7
#define D 512
#define HH 196   // H*H = 14*14
#define DT 128
#define NF (S*F)          // 640
#define NROWS_V (S*F*K)   // 4480
#define NROWS_A (S*K)     // 448
#define NOUT (S*K*F)      // 4480
#define MLP_R 16
#define NA_BLK (NROWS_A / MLP_R)   // 28
#define NV_BLK (NROWS_V / MLP_R)   // 280
#define WT 32                      // d-rows per staged W tile
#define WTILE_F4 (WT * DT / 4)     // 1024 float4 = 16 KB

// fg geometry: 16-channel tiles (16 ch x 196 hw = 12,544 B contiguous), 16 tiles
#define FG_TPB 256
#define FG_NT 16
#define FG_TILE_F4 784
#define FG_SLOTS 832   // 13 issues x 64 lanes (slots >=784 junk, never read)

// ---------------------------------------------------------------------------
// Kernel 1 (v7): fg[n][k][c] = (sum_hw feat[n][c][hw]*cam[n][k][hw]) / (cam_sum+1e-10)
// cam slice in REGISTERS (21 float4/thread, loaded once, reused across all 16
// tiles); contiguous global_load_lds staging, double-buffered. ~45-50 us
// (measured via R8 reps; near the ~41 us HBM floor).
// ---------------------------------------------------------------------------
__device__ __forceinline__ void fg_stage(const float* region, float4* dst,
                                         int wave, int lane) {
#pragma unroll
  for (int i = wave; i < 13; i += 4) {
    const int p = i * 64 + lane;
    const int ps = (p < FG_TILE_F4) ? p : 0;  // clamp tail (junk slots, never read)
    __builtin_amdgcn_global_load_lds(
        (const __attribute__((address_space(1))) void*)(region + (size_t)ps * 4),
        (__attribute__((address_space(3))) void*)(dst + i * 64), 16, 0, 0);
  }
}

__global__ __launch_bounds__(FG_TPB) void fg_kernel(
    const float* __restrict__ feat, const float* __restrict__ cam,
    float* __restrict__ fg) {
  __shared__ float4 buf[2][FG_SLOTS];   // 26,624 B
  __shared__ float inv_lds[K];

  const int t = threadIdx.x;
  const int lane = t & 63;
  const int wave = t >> 6;
  const int n = blockIdx.x >> 1;
  const int half = blockIdx.x & 1;
  const int c0blk = half * 256;
  const int cl = t >> 4;   // channel-in-tile 0..15
  const int s16 = t & 15;  // 16-way hw split

  const float* featn = feat + ((size_t)n * D + c0blk) * HH;
  const float* camn = cam + (size_t)n * K * HH;
  const float4* camf4 = reinterpret_cast<const float4*>(camn);

  // cam slice -> registers (coalesced; reused across all 16 tiles)
  float4 cq0[K], cq1[K], cq2[K], cq3[K];
#pragma unroll
  for (int k = 0; k < K; ++k) {
    cq0[k] = camf4[k * 49 + s16];
    cq1[k] = camf4[k * 49 + 16 + s16];
    cq2[k] = camf4[k * 49 + 32 + s16];
    cq3[k] = (s16 == 0) ? camf4[k * 49 + 48] : make_float4(0.f, 0.f, 0.f, 0.f);
  }

  // cam sums -> inv_lds (wave 0 butterfly)
  if (t < 64) {
    const bool act = lane < 49;
#pragma unroll
    for (int k = 0; k < K; ++k) {
      float4 cv = act ? camf4[k * 49 + lane] : make_float4(0.f, 0.f, 0.f, 0.f);
      float s = cv.x + cv.y + cv.z + cv.w;
#pragma unroll
      for (int m = 32; m >= 1; m >>= 1) s += __shfl_xor(s, m, 64);
      if (lane == 0) inv_lds[k] = 1.0f / (s + 1e-10f);
    }
  }

  fg_stage(featn, &buf[0][0], wave, lane);
  __syncthreads();  // stage(0) landed + inv_lds published

  float invr[K];
#pragma unroll
  for (int k = 0; k < K; ++k) invr[k] = inv_lds[k];

  float* fgn = fg + (size_t)n * K * D;

  for (int tt = 0; tt < FG_NT; ++tt) {
    const int cur = tt & 1;
    if (tt < FG_NT - 1)
      fg_stage(featn + (size_t)(tt + 1) * FG_TILE_F4 * 4,
               &buf[cur ^ 1][0], wave, lane);

    const float4* tb = &buf[cur][0] + cl * 49;
    const float4 f0 = tb[s16];
    const float4 f1 = tb[16 + s16];
    const float4 f2 = tb[32 + s16];
    const float4 f3 = (s16 == 0) ? tb[48] : make_float4(0.f, 0.f, 0.f, 0.f);

    float acc[K];
#pragma unroll
    for (int k = 0; k < K; ++k) {
      float a = 0.f;
      a = fmaf(f0.x, cq0[k].x, a); a = fmaf(f0.y, cq0[k].y, a);
      a = fmaf(f0.z, cq0[k].z, a); a = fmaf(f0.w, cq0[k].w, a);
      a = fmaf(f1.x, cq1[k].x, a); a = fmaf(f1.y, cq1[k].y, a);
      a = fmaf(f1.z, cq1[k].z, a); a = fmaf(f1.w, cq1[k].w, a);
      a = fmaf(f2.x, cq2[k].x, a); a = fmaf(f2.y, cq2[k].y, a);
      a = fmaf(f2.z, cq2[k].z, a); a = fmaf(f2.w, cq2[k].w, a);
      a = fmaf(f3.x, cq3[k].x, a); a = fmaf(f3.y, cq3[k].y, a);
      a = fmaf(f3.z, cq3[k].z, a); a = fmaf(f3.w, cq3[k].w, a);
      acc[k] = a;
    }
#pragma unroll
    for (int m = 1; m <= 8; m <<= 1) {
#pragma unroll
      for (int k = 0; k < K; ++k) acc[k] += __shfl_xor(acc[k], m, 64);
    }
    if (s16 == 0) {
      const int c = c0blk + tt * 16 + cl;
#pragma unroll
      for (int k = 0; k < K; ++k) fgn[k * D + c] = acc[k] * invr[k];
    }
    __syncthreads();  // next tile landed (vmcnt drained) + buf reuse guard
  }
}

// ---------------------------------------------------------------------------
// Kernel 2 (v4): BOTH MLPs; W streamed through LDS (async global_load_lds,
// double-buffered 32x128 tiles) instead of per-thread flat loads -> load
// latency hidden, VGPR stays low. 16 rows/block, 256 thr, thread = 2 rows x
// 4 cols. xs reads are half-wave broadcast; W reads ds_read_b128 2-way (free).
// ---------------------------------------------------------------------------
__device__ __forceinline__ void fma4(float4& acc, float sx, const float4& wv) {
  acc.x += sx * wv.x; acc.y += sx * wv.y; acc.z += sx * wv.z; acc.w += sx * wv.w;
}

__device__ __forceinline__ void stage_n(const float* src, float4* dst, int t,
                                        int n_f4) {
  for (int i = 0; i < n_f4; i += 256) {
    __builtin_amdgcn_global_load_lds(
        (const __attribute__((address_space(1))) void*)(src + (size_t)(i + t) * 4),
        (__attribute__((address_space(3))) void*)(dst + i + t), 16, 0, 0);
  }
}

__global__ __launch_bounds__(256) void mlp2_kernel(
    const float* __restrict__ Xa, const float* __restrict__ Xv,
    const float* __restrict__ W1a, const float* __restrict__ b1a,
    const float* __restrict__ W2a, const float* __restrict__ b2a,
    const float* __restrict__ ga, const float* __restrict__ bna,
    const float* __restrict__ W1v, const float* __restrict__ b1v,
    const float* __restrict__ W2v, const float* __restrict__ b2v,
    const float* __restrict__ gv, const float* __restrict__ bnv,
    float* __restrict__ Ta, float* __restrict__ Tv) {
  __shared__ float xs[MLP_R * D];          // 32 KB
  __shared__ float4 wbuf[2][WTILE_F4];     // 32 KB
  __shared__ float hs[MLP_R * DT];         // 8 KB
  const int t = threadIdx.x;
  const int b = blockIdx.x;

  const float *X, *W1, *b1, *W2, *b2, *g, *bn;
  float* out;
  int r0;
  if (b < NA_BLK) {
    X = Xa; W1 = W1a; b1 = b1a; W2 = W2a; b2 = b2a; g = ga; bn = bna;
    out = Ta; r0 = b * MLP_R;
  } else {
    X = Xv; W1 = W1v; b1 = b1v; W2 = W2v; b2 = b2v; g = gv; bn = bnv;
    out = Tv; r0 = (b - NA_BLK) * MLP_R;
  }

  // async-stage X rows (2048 f4) and W1 tile 0 (1024 f4)
  stage_n(X + (size_t)r0 * D, reinterpret_cast<float4*>(xs), t, MLP_R * D / 4);
  stage_n(W1, &wbuf[0][0], t, WTILE_F4);
  __syncthreads();  // all staged loads landed

  const int cg = t & 31;        // col group -> j0 = cg*4
  const int j0 = cg * 4;
  const int rp = t >> 5;        // 0..7 -> rows 2rp, 2rp+1
  const float4* x0p = reinterpret_cast<const float4*>(xs + (rp * 2) * D);
  const float4* x1p = reinterpret_cast<const float4*>(xs + (rp * 2 + 1) * D);

  // ---- layer 1: 16 tiles of 32 d-rows ----
  float4 a0 = *reinterpret_cast<const float4*>(b1 + j0);
  float4 a1 = a0;
  for (int dt = 0; dt < 16; ++dt) {
    if (dt < 15) stage_n(W1 + (size_t)(dt + 1) * WT * DT, &wbuf[(dt + 1) & 1][0], t, WTILE_F4);
    else         stage_n(W2, &wbuf[0][0], t, WTILE_F4);  // prefetch W2 tile 0
    const float4* wb = &wbuf[dt & 1][0];
#pragma unroll
    for (int d4 = 0; d4 < 8; ++d4) {
      const float4 x0 = x0p[dt * 8 + d4];
      const float4 x1 = x1p[dt * 8 + d4];
      const float4 w0 = wb[(d4 * 4 + 0) * 32 + cg];
      const float4 w1 = wb[(d4 * 4 + 1) * 32 + cg];
      const float4 w2 = wb[(d4 * 4 + 2) * 32 + cg];
      const float4 w3 = wb[(d4 * 4 + 3) * 32 + cg];
      fma4(a0, x0.x, w0); fma4(a0, x0.y, w1); fma4(a0, x0.z, w2); fma4(a0, x0.w, w3);
      fma4(a1, x1.x, w0); fma4(a1, x1.y, w1); fma4(a1, x1.z, w2); fma4(a1, x1.w, w3);
    }
    __syncthreads();  // stage(dt+1) landed; all waves done reading wbuf[dt&1]
  }

  // relu -> hs
  a0.x = fmaxf(a0.x, 0.f); a0.y = fmaxf(a0.y, 0.f);
  a0.z = fmaxf(a0.z, 0.f); a0.w = fmaxf(a0.w, 0.f);
  a1.x = fmaxf(a1.x, 0.f); a1.y = fmaxf(a1.y, 0.f);
  a1.z = fmaxf(a1.z, 0.f); a1.w = fmaxf(a1.w, 0.f);
  *reinterpret_cast<float4*>(hs + (rp * 2) * DT + j0) = a0;
  *reinterpret_cast<float4*>(hs + (rp * 2 + 1) * DT + j0) = a1;
  __syncthreads();  // hs published (W2 tile 0 already landed at loop-end barrier)

  const float4* h0p = reinterpret_cast<const float4*>(hs + (rp * 2) * DT);
  const float4* h1p = reinterpret_cast<const float4*>(hs + (rp * 2 + 1) * DT);

  // ---- layer 2: 4 tiles of 32 d-rows ----
  float4 c0 = *reinterpret_cast<const float4*>(b2 + j0);
  float4 c1 = c0;
  for (int dt = 0; dt < 4; ++dt) {
    if (dt < 3) stage_n(W2 + (size_t)(dt + 1) * WT * DT, &wbuf[(dt + 1) & 1][0], t, WTILE_F4);
    const float4* wb = &wbuf[dt & 1][0];
#pragma unroll
    for (int d4 = 0; d4 < 8; ++d4) {
      const float4 x0 = h0p[dt * 8 + d4];
      const float4 x1 = h1p[dt * 8 + d4];
      const float4 w0 = wb[(d4 * 4 + 0) * 32 + cg];
      const float4 w1 = wb[(d4 * 4 + 1) * 32 + cg];
      const float4 w2 = wb[(d4 * 4 + 2) * 32 + cg];
      const float4 w3 = wb[(d4 * 4 + 3) * 32 + cg];
      fma4(c0, x0.x, w0); fma4(c0, x0.y, w1); fma4(c0, x0.z, w2); fma4(c0, x0.w, w3);
      fma4(c1, x1.x, w0); fma4(c1, x1.y, w1); fma4(c1, x1.z, w2); fma4(c1, x1.w, w3);
    }
    __syncthreads();
  }

  // affine epilogue
  const float4 gvv = *reinterpret_cast<const float4*>(g + j0);
  const float4 bv = *reinterpret_cast<const float4*>(bn + j0);
  float4 o0, o1;
  o0.x = c0.x * gvv.x + bv.x; o0.y = c0.y * gvv.y + bv.y;
  o0.z = c0.z * gvv.z + bv.z; o0.w = c0.w * gvv.w + bv.w;
  o1.x = c1.x * gvv.x + bv.x; o1.y = c1.y * gvv.y + bv.y;
  o1.z = c1.z * gvv.z + bv.z; o1.w = c1.w * gvv.w + bv.w;
  *reinterpret_cast<float4*>(out + (size_t)(r0 + rp * 2) * DT + j0) = o0;
  *reinterpret_cast<float4*>(out + (size_t)(r0 + rp * 2 + 1) * DT + j0) = o1;
}

// ---------------------------------------------------------------------------
// Kernel 3: losses + masks (8 units/block, 32-lane groups).
// ---------------------------------------------------------------------------
__global__ __launch_bounds__(256) void loss_kernel(
    const float* __restrict__ Ta, const float* __restrict__ Tv,
    const float* __restrict__ pred_a, const float* __restrict__ pred_v,
    const int* __restrict__ perm_idx, const int* __restrict__ cls_idx,
    float* __restrict__ out) {
  const int t = threadIdx.x;
  const int sub = t & 31;
  const int idx = blockIdx.x * 8 + (t >> 5);
  const int f = idx % F;
  const int k = (idx / F) % K;
  const int s = idx / (K * F);

  const int p = perm_idx[idx];
  const int c = cls_idx[idx];
  const int rowd = ((s ^ 1) * F + p) * K + c;

  float4 ta = reinterpret_cast<const float4*>(Ta)[(s * K + k) * 32 + sub];
  float4 tv = reinterpret_cast<const float4*>(Tv)[((s * F + f) * K + k) * 32 + sub];
  float4 td = reinterpret_cast<const float4*>(Tv)[rowd * 32 + sub];
  float d1 = 0.f, d2 = 0.f, e;
  e = ta.x - tv.x; d1 += e * e;
  e = ta.y - tv.y; d1 += e * e;
  e = ta.z - tv.z; d1 += e * e;
  e = ta.w - tv.w; d1 += e * e;
  e = ta.x - td.x; d2 += e * e;
  e = ta.y - td.y; d2 += e * e;
  e = ta.z - td.z; d2 += e * e;
  e = ta.w - td.w; d2 += e * e;
#pragma unroll
  for (int m = 16; m >= 1; m >>= 1) {
    d1 += __shfl_xor(d1, m, 64);
    d2 += __shfl_xor(d2, m, 64);
  }
  if (sub == 0) {
    float pa = pred_a[s * K + k];
    bool act = pa > 0.3f;
    int num = (int)floorf(pa * (float)F);
    float pvv = pred_v[(s * F + f) * K + k];
    float sg = 1.0f / (1.0f + expf(-pvv));
    bool mco = act && (sg > 0.3f);
    bool mdi = act && (f < num);
    float lco = d1 * (1.0f / 128.0f);
    float ldi = d2 * (1.0f / 128.0f);
    out[idx] = mco ? lco : 0.0f;
    out[NOUT + idx] = mdi ? ldi : 0.0f;
    out[2 * NOUT + idx] = mco ? 1.0f : 0.0f;
    out[3 * NOUT + idx] = mdi ? 1.0f : 0.0f;
  }
}

extern "C" void kernel_launch(void* const* d_in, const int* in_sizes, int n_in,
                              void* d_out, int out_size, void* d_ws, size_t ws_size,
                              hipStream_t stream) {
  const float* feat_a     = (const float*)d_in[0];
  const float* pred_a     = (const float*)d_in[1];
  const float* feat_v_raw = (const float*)d_in[2];
  const float* pred_v     = (const float*)d_in[3];
  const float* cam        = (const float*)d_in[4];
  const float* W1a = (const float*)d_in[5];
  const float* b1a = (const float*)d_in[6];
  const float* W2a = (const float*)d_in[7];
  const float* b2a = (const float*)d_in[8];
  const float* ga  = (const float*)d_in[9];
  const float* bna = (const float*)d_in[10];
  const float* W1v = (const float*)d_in[11];
  const float* b1v = (const float*)d_in[12];
  const float* W2v = (const float*)d_in[13];
  const float* b2v = (const float*)d_in[14];
  const float* gv  = (const float*)d_in[15];
  const float* bnv = (const float*)d_in[16];
  const int* perm_idx = (const int*)d_in[17];
  const int* cls_idx  = (const int*)d_in[18];
  float* out = (float*)d_out;

  // workspace layout (floats): fg[640*7*512] | Ta[448*128] | Tv[4480*128]
  float* ws = (float*)d_ws;
  float* fg = ws;
  float* Ta = fg + (size_t)NF * K * D;
  float* Tv = Ta + (size_t)NROWS_A * DT;

  fg_kernel<<<NF * 2, FG_TPB, 0, stream>>>(feat_v_raw, cam, fg);
  mlp2_kernel<<<NA_BLK + NV_BLK, 256, 0, stream>>>(
      feat_a, fg, W1a, b1a, W2a, b2a, ga, bna,
      W1v, b1v, W2v, b2v, gv, bnv, Ta, Tv);
  loss_kernel<<<NOUT / 8, 256, 0, stream>>>(Ta, Tv, pred_a, pred_v, perm_idx,
                                            cls_idx, out);
}